// Round 3
// baseline (200.640 us; speedup 1.0000x reference)
//
#include <hip/hip_runtime.h>

typedef unsigned short u16;
typedef __attribute__((ext_vector_type(4))) float f32x4;
typedef __attribute__((ext_vector_type(8))) short bf16x8;
typedef __attribute__((ext_vector_type(4))) u16 u16x4;
typedef __attribute__((ext_vector_type(8))) u16 u16x8;

__device__ __forceinline__ u16 f2bf(float f) {
    unsigned u = __float_as_uint(f);
    unsigned r = (u + 0x7FFFu + ((u >> 16) & 1u)) >> 16;
    return (u16)r;
}

__device__ __forceinline__ void gld16(const void* g, void* l) {
    __builtin_amdgcn_global_load_lds(
        (const __attribute__((address_space(1))) unsigned*)g,
        (__attribute__((address_space(3))) unsigned*)l,
        16, 0, 0);
}

// ---------------- cast fp32 -> bf16, vectorized ----------------
__global__ __launch_bounds__(256) void cast_kernel(const float* __restrict__ in,
                                                   u16* __restrict__ out, int n4) {
    int i = blockIdx.x * blockDim.x + threadIdx.x;
    int stride = gridDim.x * blockDim.x;
    for (; i < n4; i += stride) {
        f32x4 v = ((const f32x4*)in)[i];
        u16x4 o;
        o[0] = f2bf(v[0]); o[1] = f2bf(v[1]); o[2] = f2bf(v[2]); o[3] = f2bf(v[3]);
        ((u16x4*)out)[i] = o;
    }
}

// ---------------- 256x256 8-phase bf16 GEMM: C = A[M,K] * B[N,K]^T ----------------
// 512 threads = 8 waves (2M x 4N), per-wave C = 128x64 (8x4 16x16 frags).
// BK=64, LDS 128KB: A[2][256][64], B[2][256][64] bf16, XOR-swizzled 16B slots
// (slot ^= row&7) with pre-swizzled global source (rule 21: linear LDS dest).
// Race-free stage slots (re-derived): a wave's A reads span BOTH A halves
// (P1: rows wm*128+[0,64), P3: +[64,128)), so tile t+2's A cannot be staged in
// iteration t. Instead: P1/P2 stage tile t+1's Ah0/Ah1 (buffer db^1, idle this
// iter; last read drained at t-1.P3-end). B drains at P2-end -> P3/P4 stage
// tile t+2's Bh0/Bh1 (buffer db). vmcnt(4) at P4 = tile t+1 fully landed,
// t.P3/P4's 4 loads in flight. vmcnt(0) when t+2>=NT (no trailing loads).
template <int OUT_F32>
__global__ __launch_bounds__(512, 2) void gemm256(
    const u16* __restrict__ A, const u16* __restrict__ Bm, void* __restrict__ Cv,
    int K, int lda, int ldb, int ldc,
    long long sA, long long sB, long long sC, float scale) {
    extern __shared__ char smem[];
    const u16* Ab = A + (long long)blockIdx.z * sA;
    const u16* Bb = Bm + (long long)blockIdx.z * sB;

    const int tid  = threadIdx.x;
    const int lane = tid & 63;
    const int w    = tid >> 6;
    const int wm   = w >> 2;   // 0..1
    const int wn   = w & 3;    // 0..3
    const int rowBase = blockIdx.x << 8;
    const int colBase = blockIdx.y << 8;
    const int NT = K >> 6;
    const int aRow = lane & 15;

    // stage half-tile h of tile `tile`: h0=Ah0, h1=Bh0, h2=Bh1, h3=Ah1
    auto stage = [&](int tile, int h) {
        if (tile >= NT) return;
        const int db = tile & 1;
        const int kt = tile << 6;
        const u16* mat; int ldm, rb, halfRow; char* region;
        if (h == 0)      { mat = Ab; ldm = lda; rb = rowBase; halfRow = 0;   region = smem + db * 32768; }
        else if (h == 1) { mat = Bb; ldm = ldb; rb = colBase; halfRow = 0;   region = smem + 65536 + db * 32768; }
        else if (h == 2) { mat = Bb; ldm = ldb; rb = colBase; halfRow = 128; region = smem + 65536 + db * 32768; }
        else             { mat = Ab; ldm = lda; rb = rowBase; halfRow = 128; region = smem + db * 32768; }
#pragma unroll
        for (int i = 0; i < 2; i++) {
            int o    = ((i * 8 + w) << 10) + lane * 16;  // linear byte in 16KB half
            int r    = o >> 7;                            // row within half
            int slot = (o >> 4) & 7;                      // 16B slot in 128B row
            const u16* g = mat + (size_t)(rb + halfRow + r) * ldm + kt +
                           ((slot ^ (r & 7)) << 3);       // inverse-swizzled source
            gld16(g, region + halfRow * 128 + ((i * 8 + w) << 10));  // wave-uniform dest
        }
    };
    auto ldA = [&](int db, int row, int ks) -> bf16x8 {
        int byte = db * 32768 + row * 128 + ((((ks << 2) | (lane >> 4)) ^ (row & 7)) << 4);
        return *(const bf16x8*)(smem + byte);
    };
    auto ldB = [&](int db, int row, int ks) -> bf16x8 {
        int byte = 65536 + db * 32768 + row * 128 + ((((ks << 2) | (lane >> 4)) ^ (row & 7)) << 4);
        return *(const bf16x8*)(smem + byte);
    };

    f32x4 acc[8][4] = {};
    bf16x8 aF[4][2], b0[2][2], b1[2][2];

    // prologue: tile0 all halves, tile1's B halves; tile0 landed (4 left)
    stage(0, 0); stage(0, 3); stage(0, 1); stage(0, 2);
    stage(1, 1); stage(1, 2);
    asm volatile("s_waitcnt vmcnt(4)" ::: "memory");
    __builtin_amdgcn_sched_barrier(0);
    __builtin_amdgcn_s_barrier();
    __builtin_amdgcn_sched_barrier(0);

    for (int t = 0; t < NT; ++t) {
        const int db = t & 1;
        // ---- P1: read A[rows wm*128+0..63] + B[rows wn*64+0..31]; stage (t+1).Ah0; MFMA quad (0,0) ----
#pragma unroll
        for (int m = 0; m < 4; m++)
#pragma unroll
            for (int ks = 0; ks < 2; ks++)
                aF[m][ks] = ldA(db, wm * 128 + m * 16 + aRow, ks);
#pragma unroll
        for (int n = 0; n < 2; n++)
#pragma unroll
            for (int ks = 0; ks < 2; ks++)
                b0[n][ks] = ldB(db, wn * 64 + n * 16 + aRow, ks);
        stage(t + 1, 0);
        __builtin_amdgcn_s_barrier();
        asm volatile("s_waitcnt lgkmcnt(0)" ::: "memory");
        __builtin_amdgcn_sched_barrier(0);
        __builtin_amdgcn_s_setprio(1);
#pragma unroll
        for (int m = 0; m < 4; m++)
#pragma unroll
            for (int n = 0; n < 2; n++)
#pragma unroll
                for (int ks = 0; ks < 2; ks++)
                    acc[m][n] = __builtin_amdgcn_mfma_f32_16x16x32_bf16(
                        aF[m][ks], b0[n][ks], acc[m][n], 0, 0, 0);
        __builtin_amdgcn_s_setprio(0);
        __builtin_amdgcn_s_barrier();
        __builtin_amdgcn_sched_barrier(0);
        // ---- P2: read B[rows wn*64+32..63]; stage (t+1).Ah1; MFMA quad (0,1) ----
#pragma unroll
        for (int n = 0; n < 2; n++)
#pragma unroll
            for (int ks = 0; ks < 2; ks++)
                b1[n][ks] = ldB(db, wn * 64 + (n + 2) * 16 + aRow, ks);
        stage(t + 1, 3);
        __builtin_amdgcn_s_barrier();
        asm volatile("s_waitcnt lgkmcnt(0)" ::: "memory");
        __builtin_amdgcn_sched_barrier(0);
        __builtin_amdgcn_s_setprio(1);
#pragma unroll
        for (int m = 0; m < 4; m++)
#pragma unroll
            for (int n = 0; n < 2; n++)
#pragma unroll
                for (int ks = 0; ks < 2; ks++)
                    acc[m][n + 2] = __builtin_amdgcn_mfma_f32_16x16x32_bf16(
                        aF[m][ks], b1[n][ks], acc[m][n + 2], 0, 0, 0);
        __builtin_amdgcn_s_setprio(0);
        __builtin_amdgcn_s_barrier();
        __builtin_amdgcn_sched_barrier(0);
        // ---- P3: read A[rows wm*128+64..127]; stage (t+2).Bh0; MFMA quad (1,1) ----
#pragma unroll
        for (int m = 0; m < 4; m++)
#pragma unroll
            for (int ks = 0; ks < 2; ks++)
                aF[m][ks] = ldA(db, wm * 128 + (m + 4) * 16 + aRow, ks);
        stage(t + 2, 1);
        __builtin_amdgcn_s_barrier();
        asm volatile("s_waitcnt lgkmcnt(0)" ::: "memory");
        __builtin_amdgcn_sched_barrier(0);
        __builtin_amdgcn_s_setprio(1);
#pragma unroll
        for (int m = 0; m < 4; m++)
#pragma unroll
            for (int n = 0; n < 2; n++)
#pragma unroll
                for (int ks = 0; ks < 2; ks++)
                    acc[m + 4][n + 2] = __builtin_amdgcn_mfma_f32_16x16x32_bf16(
                        aF[m][ks], b1[n][ks], acc[m + 4][n + 2], 0, 0, 0);
        __builtin_amdgcn_s_setprio(0);
        __builtin_amdgcn_s_barrier();
        __builtin_amdgcn_sched_barrier(0);
        // ---- P4: stage (t+2).Bh1; vmcnt; MFMA quad (1,0) (reuse aF,b0) ----
        stage(t + 2, 2);
        if (t + 2 < NT) { asm volatile("s_waitcnt vmcnt(4)" ::: "memory"); }
        else            { asm volatile("s_waitcnt vmcnt(0)" ::: "memory"); }
        __builtin_amdgcn_sched_barrier(0);
        __builtin_amdgcn_s_barrier();
        __builtin_amdgcn_s_setprio(1);
#pragma unroll
        for (int m = 0; m < 4; m++)
#pragma unroll
            for (int n = 0; n < 2; n++)
#pragma unroll
                for (int ks = 0; ks < 2; ks++)
                    acc[m + 4][n] = __builtin_amdgcn_mfma_f32_16x16x32_bf16(
                        aF[m][ks], b0[n][ks], acc[m + 4][n], 0, 0, 0);
        __builtin_amdgcn_s_setprio(0);
        __builtin_amdgcn_s_barrier();
        __builtin_amdgcn_sched_barrier(0);
    }

    // epilogue: C/D layout col = lane&15, row = (lane>>4)*4 + j
    const int row0 = rowBase + wm * 128 + ((lane >> 4) << 2);
    const int col0 = colBase + wn * 64 + (lane & 15);
    long long cb = (long long)blockIdx.z * sC;
#pragma unroll
    for (int m = 0; m < 8; m++) {
#pragma unroll
        for (int n = 0; n < 4; n++) {
            f32x4 v = acc[m][n];
#pragma unroll
            for (int j = 0; j < 4; j++) {
                size_t idx = (size_t)(row0 + m * 16 + j) * ldc + (col0 + n * 16);
                if (OUT_F32)
                    ((float*)Cv)[cb + idx] = v[j] * scale;
                else
                    ((u16*)Cv)[cb + idx] = f2bf(v[j] * scale);
            }
        }
    }
}

// ---------------- row softmax: fp32 scores [rows,2048] -> bf16 P ----------------
__global__ __launch_bounds__(256) void softmax_kernel(const float* __restrict__ S,
                                                      u16* __restrict__ P) {
    const int row  = blockIdx.x;
    const int tid  = threadIdx.x;
    const int lane = tid & 63;
    const int wid  = tid >> 6;
    const float* s = S + (size_t)row * 2048;

    f32x4 v0 = ((const f32x4*)s)[tid * 2];
    f32x4 v1 = ((const f32x4*)s)[tid * 2 + 1];

    float m = v0[0];
#pragma unroll
    for (int j = 1; j < 4; j++) m = fmaxf(m, v0[j]);
#pragma unroll
    for (int j = 0; j < 4; j++) m = fmaxf(m, v1[j]);
#pragma unroll
    for (int off = 32; off >= 1; off >>= 1) m = fmaxf(m, __shfl_xor(m, off));

    __shared__ float red[8];
    if (lane == 0) red[wid] = m;
    __syncthreads();
    m = fmaxf(fmaxf(red[0], red[1]), fmaxf(red[2], red[3]));

    float e[8];
    float sum = 0.f;
#pragma unroll
    for (int j = 0; j < 4; j++) { e[j] = __expf(v0[j] - m); sum += e[j]; }
#pragma unroll
    for (int j = 0; j < 4; j++) { e[4 + j] = __expf(v1[j] - m); sum += e[4 + j]; }
#pragma unroll
    for (int off = 32; off >= 1; off >>= 1) sum += __shfl_xor(sum, off);
    if (lane == 0) red[4 + wid] = sum;
    __syncthreads();
    sum = (red[4] + red[5]) + (red[6] + red[7]);

    float inv = 1.0f / sum;
    u16x8 o;
#pragma unroll
    for (int j = 0; j < 8; j++) o[j] = f2bf(e[j] * inv);
    ((u16x8*)(P + (size_t)row * 2048))[tid] = o;
}

// ---------------- launch ----------------
extern "C" void kernel_launch(void* const* d_in, const int* in_sizes, int n_in,
                              void* d_out, int out_size, void* d_ws, size_t ws_size,
                              hipStream_t stream) {
    const float* x  = (const float*)d_in[0];
    const float* Wk = (const float*)d_in[1];
    const float* Wq = (const float*)d_in[2];
    const float* Wv = (const float*)d_in[3];
    float* out = (float*)d_out;
    char* ws = (char*)d_ws;
    const size_t MB = 1u << 20;

    // layout (144MB total):
    u16* QK   = (u16*)(ws);             // 32MB [8192][2048]: cols 0-1023 Q, 1024-2047 K
    u16* VT   = (u16*)(ws + 32 * MB);   // 16MB [1024][8192] = V^T, col = b*2048+s
    u16* Pb   = (u16*)(ws + 48 * MB);   // 32MB [4][2048][2048] softmax weights
    u16* xb   = (u16*)(ws + 80 * MB);   // 16MB [8192][1024]
    u16* Wqk  = (u16*)(ws + 96 * MB);   // 4MB  [2048][1024]: rows 0-1023 Wq, 1024-2047 Wk
    u16* Wvb  = (u16*)(ws + 100 * MB);  // 2MB
    float* sc = (float*)(ws + 80 * MB); // 64MB [4][2048][2048] (overlays xb/W, dead by then)

    hipFuncSetAttribute((const void*)gemm256<0>, hipFuncAttributeMaxDynamicSharedMemorySize, 131072);
    hipFuncSetAttribute((const void*)gemm256<1>, hipFuncAttributeMaxDynamicSharedMemorySize, 131072);

    cast_kernel<<<2048, 256, 0, stream>>>(x, xb, 8388608 / 4);
    cast_kernel<<<1024, 256, 0, stream>>>(Wq, Wqk, 1048576 / 4);
    cast_kernel<<<1024, 256, 0, stream>>>(Wk, Wqk + 1048576, 1048576 / 4);
    cast_kernel<<<1024, 256, 0, stream>>>(Wv, Wvb, 1048576 / 4);

    // [Q|K] = x @ [Wq|Wk]^T : M=8192, N=2048, K=1024 (256 blocks, full chip)
    gemm256<0><<<dim3(32, 8, 1), 512, 131072, stream>>>(
        xb, Wqk, QK, 1024, 1024, 1024, 2048, 0, 0, 0, 1.0f);
    // V^T = Wv @ x^T : M=1024, N=8192, K=1024 (128 blocks)
    gemm256<0><<<dim3(4, 32, 1), 512, 131072, stream>>>(
        Wvb, xb, VT, 1024, 1024, 1024, 8192, 0, 0, 0, 1.0f);
    // scores = (Q @ K^T)/32 : per-batch M=N=2048, K=1024 (256 blocks)
    gemm256<1><<<dim3(8, 8, 4), 512, 131072, stream>>>(
        QK, QK + 1024, sc, 1024, 2048, 2048, 2048,
        2048LL * 2048, 2048LL * 2048, 2048LL * 2048, 0.03125f);
    // P = softmax rows
    softmax_kernel<<<8192, 256, 0, stream>>>(sc, Pb);
    // ctx = P @ (V^T)^T : per-batch M=2048, N=1024, K=2048 (128 blocks)
    gemm256<1><<<dim3(8, 4, 4), 512, 131072, stream>>>(
        Pb, VT, out, 2048, 2048, 8192, 1024,
        2048LL * 2048, 2048LL, 2048LL * 1024, 1.0f);
}